// Round 10
// baseline (1539.885 us; speedup 1.0000x reference)
//
#include <hip/hip_runtime.h>
#include <hip/hip_bf16.h>
#include <hip/hip_fp16.h>

// GRU B=64 S=2048 I=256 H=256, fp32 in/out.
// Phase 1: XG[m][768] = x@[Wz|Wr|Wh] + bias  (fp16 MFMA, fp32 accum)
// Phase 2 (R10): i8 K=64 MFMA recurrence with SPLIT-K PHASE PIPELINE.
//   R9 calibration: MFMA pipe busy = 779cy/step == 773 floor; the other
//   680cy is the serial tail (VALU+trans, 4 waves lockstep) + barrier +
//   ds latency. Fix: 2 K-phases, 2 barriers; waves 0-7 own h_lo (cols
//   0-127), waves 8-15 own h_hi. B's tail(t-1) runs DURING ks01 MFMA of
//   step t (separate pipes, m114) -> only A's tail exposed. B ping-pongs
//   two acc sets (2x-unrolled body, static names). setprio now has
//   phase-diverse waves to arbitrate.

#define S_LEN 2048
#define BATCH 64
#define HDIM  256
#define NGATE 768
#define M_TOTAL (BATCH * S_LEN)  // 131072

typedef _Float16 h8_t __attribute__((ext_vector_type(8)));
typedef float    f32x4 __attribute__((ext_vector_type(4)));
typedef int      i32x4 __attribute__((ext_vector_type(4)));

static __device__ __forceinline__ float h2f(unsigned short s) {
    _Float16 h; __builtin_memcpy(&h, &s, 2); return (float)h;
}
static __device__ __forceinline__ unsigned short f2h(float f) {
    _Float16 h = (_Float16)f; unsigned short s; __builtin_memcpy(&s, &h, 2); return s;
}

static __device__ __forceinline__ float sigmoid_fast(float x) {
    float e = __builtin_amdgcn_exp2f(-1.44269504088896341f * x);
    return __builtin_amdgcn_rcpf(1.0f + e);
}
static __device__ __forceinline__ float tanh_fast(float x) {
    return 2.0f * sigmoid_fast(2.0f * x) - 1.0f;
}

// ---------------- prep kernels ----------------

__global__ void k_cvt_x(const float4* __restrict__ x4, ushort4* __restrict__ xh4) {
    int i = blockIdx.x * blockDim.x + threadIdx.x;
    float4 v = x4[i];
    ushort4 o;
    o.x = f2h(v.x); o.y = f2h(v.y); o.z = f2h(v.z); o.w = f2h(v.w);
    xh4[i] = o;
}

__global__ void k_prep_w(const float* __restrict__ Wz, const float* __restrict__ Wr,
                         const float* __restrict__ Wh,
                         const float* __restrict__ bz, const float* __restrict__ br,
                         const float* __restrict__ bh,
                         const float* __restrict__ buz, const float* __restrict__ bur,
                         unsigned short* __restrict__ Wt, float* __restrict__ biascat) {
    int n = blockIdx.x;       // 0..767
    int k = threadIdx.x;      // 0..255
    int g = n >> 8, h = n & 255;
    const float* W = (g == 0) ? Wz : (g == 1) ? Wr : Wh;
    Wt[n * 256 + k] = f2h(W[k * 256 + h]);
    if (k == 0) {
        float bias = (g == 0) ? (bz[h] + buz[h]) : (g == 1) ? (br[h] + bur[h]) : bh[h];
        biascat[n] = bias;
    }
}

// int8 B-fragments for mfma_i32_16x16x64_i8 + per-column descale factors.
// Lane l supplies B[k][col]: col = nt*16 + (l&15), k = ks*64 + (l>>4)*16 + e.
// Ufrag[(((g*16+nt)*4+ks)*64 + l)*16 + e] = round(U_g[k][col] * s_col)
// invU[g*256+col] = maxk|U| / (127*127)
__global__ void k_prep_uq(const float* __restrict__ Uz, const float* __restrict__ Ur,
                          const float* __restrict__ Uh,
                          signed char* __restrict__ Ufrag, float* __restrict__ invU) {
    int blk = blockIdx.x;           // g*256 + col
    int g = blk >> 8, col = blk & 255;
    int k = threadIdx.x;            // 0..255
    const float* U = (g == 0) ? Uz : (g == 1) ? Ur : Uh;
    float v = U[k * 256 + col];
    __shared__ float red[256];
    red[k] = fabsf(v);
    __syncthreads();
    for (int off = 128; off > 0; off >>= 1) {
        if (k < off) red[k] = fmaxf(red[k], red[k + off]);
        __syncthreads();
    }
    float m = red[0];
    float s = (m > 0.0f) ? 127.0f / m : 0.0f;
    int q = __float2int_rn(v * s);
    q = max(-127, min(127, q));
    int ks = k >> 6, l4 = (k >> 4) & 3, e = k & 15;
    int l = l4 * 16 + (col & 15), nt = col >> 4;
    Ufrag[((size_t)(((g * 16 + nt) * 4 + ks) * 64 + l)) * 16 + e] = (signed char)q;
    if (k == 0) invU[g * 256 + col] = m * (1.0f / 16129.0f);
}

// ---------------- phase 1: input GEMM ----------------

#define LDT 264  // 256 + 8 halves per LDS row

__global__ __launch_bounds__(256) void k_gemm_x(const unsigned short* __restrict__ Xh,
                                                const unsigned short* __restrict__ Wt,
                                                const float* __restrict__ biascat,
                                                unsigned short* __restrict__ XG) {
    __shared__ unsigned short As[128 * LDT];
    __shared__ unsigned short Bs[128 * LDT];
    int tid = threadIdx.x;
    int m0 = blockIdx.x * 128;
    int n0 = blockIdx.y * 128;

    {
        const unsigned short* ga = Xh + (size_t)m0 * 256;
        const unsigned short* gb = Wt + (size_t)n0 * 256;
#pragma unroll
        for (int i = 0; i < 16; i++) {
            int chunk = tid + i * 256;
            int row = chunk >> 5;
            int c8  = (chunk & 31) * 8;
            uint4 va = *(const uint4*)(ga + row * 256 + c8);
            *(uint4*)(As + row * LDT + c8) = va;
            uint4 vb = *(const uint4*)(gb + row * 256 + c8);
            *(uint4*)(Bs + row * LDT + c8) = vb;
        }
    }
    __syncthreads();

    int lane = tid & 63, wv = tid >> 6;
    int mw = (wv & 1) * 64, nw = (wv >> 1) * 64;
    int lr = lane & 15, lg = lane >> 4;

    f32x4 acc[4][4] = {};
#pragma unroll
    for (int k = 0; k < 8; k++) {
        h8_t a[4], b[4];
#pragma unroll
        for (int i = 0; i < 4; i++)
            a[i] = *(const h8_t*)(As + (mw + i * 16 + lr) * LDT + k * 32 + lg * 8);
#pragma unroll
        for (int jj = 0; jj < 4; jj++)
            b[jj] = *(const h8_t*)(Bs + (nw + jj * 16 + lr) * LDT + k * 32 + lg * 8);
#pragma unroll
        for (int i = 0; i < 4; i++)
#pragma unroll
            for (int jj = 0; jj < 4; jj++)
                acc[i][jj] = __builtin_amdgcn_mfma_f32_16x16x32_f16(a[i], b[jj], acc[i][jj], 0, 0, 0);
    }

#pragma unroll
    for (int jj = 0; jj < 4; jj++) {
        int gcol = n0 + nw + jj * 16 + lr;
        float bias = biascat[gcol];
#pragma unroll
        for (int i = 0; i < 4; i++) {
            int grow = m0 + mw + i * 16 + lg * 4;
#pragma unroll
            for (int r = 0; r < 4; r++) {
                XG[(size_t)(grow + r) * NGATE + gcol] = f2h(acc[i][jj][r] + bias);
            }
        }
    }
}

// ---------------- phase 2: recurrence (i8 MFMA, split-K pipeline) -----
// 64 WGs x 1024 threads (16 waves, 4/SIMD). Wave w owns N-tile w.
// Group A = waves 0-7 (cols 0-127 = h_lo), B = waves 8-15 (h_hi).
// Iter t: [ks01 MFMA(h_lo) || B-tail(t-1)->h_hi] midbar [ks23 MFMA(h_hi)]
//         A-tail(t)->h_lo, endbar.

__global__ __launch_bounds__(1024) __attribute__((amdgpu_waves_per_eu(4, 4)))
void k_gru(const i32x4* __restrict__ Ufrag,
           const float* __restrict__ invU,
           const unsigned short* __restrict__ XG,
           const float* __restrict__ buh,
           float* __restrict__ out) {
    __shared__ __align__(16) signed char hb[2][256];
    int tid = threadIdx.x;
    int lane = tid & 63, w = tid >> 6;      // w = N-tile index, 0..15
    int l4 = lane >> 4, lc = lane & 15;
    int b = blockIdx.x;
    int c = w * 16 + lc;                     // owned gate-column
    bool grpA = (w < 8);

    // preamble: 12 i8 B-fragments = U[:, wave's 16 cols], 3 gates
    i32x4 uf[3][4];
#pragma unroll
    for (int g = 0; g < 3; g++)
#pragma unroll
        for (int ks = 0; ks < 4; ks++)
            uf[g][ks] = Ufrag[(size_t)((g * 16 + w) * 4 + ks) * 64 + lane];
#pragma unroll
    for (int g = 0; g < 3; g++)
#pragma unroll
        for (int ks = 0; ks < 4; ks++)
            asm volatile("" : "+v"(uf[g][ks]));

    float invz = invU[0 * 256 + c], invr = invU[1 * 256 + c], invh = invU[2 * 256 + c];
    float buh_c = buh[c];

    if (tid < 64) ((int*)hb[0])[tid] = 0;   // h(-1) = 0

    const unsigned short* xb = XG + (size_t)b * S_LEN * NGATE;
    float* ob = out + (size_t)b * S_LEN * HDIM;

    const unsigned short* xp = xb + c;   // advancing gate-input pointer
    unsigned short pz = xp[0], pr = xp[256], ph = xp[512];  // x(0)
    xp += NGATE;
    float hm = 0.0f;

    // 2 MFMA K-slices (6 MFMAs) into acc, reading hrow
    auto mfma2 = [&](i32x4* acc, const signed char* hrow, int ksBase) {
        __builtin_amdgcn_s_setprio(1);
#pragma unroll
        for (int i = 0; i < 2; i++) {
            int ks = ksBase + i;
            i32x4 a = *(const i32x4*)(hrow + ks * 64 + l4 * 16);
            acc[0] = __builtin_amdgcn_mfma_i32_16x16x64_i8(a, uf[0][ks], acc[0], 0, 0, 0);
            acc[1] = __builtin_amdgcn_mfma_i32_16x16x64_i8(a, uf[1][ks], acc[1], 0, 0, 0);
            acc[2] = __builtin_amdgcn_mfma_i32_16x16x64_i8(a, uf[2][ks], acc[2], 0, 0, 0);
        }
        __builtin_amdgcn_s_setprio(0);
    };

    // gate tail for step t: consume acc + current pz/pr/ph, update hm,
    // store out[t], write h_q to hdst, then load next x and advance xp.
    auto tail = [&](const i32x4* acc, int t, signed char* hdst) {
        float z = sigmoid_fast(h2f(pz) + (float)acc[0][0] * invz);
        float r = sigmoid_fast(h2f(pr) + (float)acc[1][0] * invr);
        float cd = tanh_fast(h2f(ph) + r * ((float)acc[2][0] * invh + buh_c));
        hm = (1.0f - z) * hm + z * cd;
        if (lane < 16) {
            ob[(size_t)t * HDIM + c] = hm;
            hdst[c] = (signed char)__float2int_rn(hm * 127.0f);
        }
        pz = xp[0]; pr = xp[256]; ph = xp[512];
        xp += NGATE;
    };

    i32x4 P[3] = {}, Q[3] = {};
    __syncthreads();                         // hb[0] zero visible

    // ---- prologue: t=0 (cur=0; both halves of hb[0] pre-zeroed) ----
    mfma2(P, hb[0], 0);
    mfma2(P, hb[0], 2);
    if (grpA) tail(P, 0, hb[1]);             // h_lo(0) -> hb[1]
    __syncthreads();

    // ---- main loop: pairs (t=2k+1 [cur=1], t=2k+2 [cur=0]) ----
    for (int k = 0; k < 1023; ++k) {
        int t1 = 2 * k + 1;
        // body ODD: cur=1, NEW=Q, PREV=P
        Q[0] = (i32x4){}; Q[1] = (i32x4){}; Q[2] = (i32x4){};
        mfma2(Q, hb[1], 0);
        if (!grpA) tail(P, t1 - 1, hb[1]);   // h_hi(t1-1) -> hb[1]
        __syncthreads();
        mfma2(Q, hb[1], 2);
        if (grpA) tail(Q, t1, hb[0]);        // h_lo(t1) -> hb[0]
        __syncthreads();
        // body EVEN: t=t1+1, cur=0, NEW=P, PREV=Q
        P[0] = (i32x4){}; P[1] = (i32x4){}; P[2] = (i32x4){};
        mfma2(P, hb[0], 0);
        if (!grpA) tail(Q, t1, hb[0]);       // h_hi(t1) -> hb[0]
        __syncthreads();
        mfma2(P, hb[0], 2);
        if (grpA) tail(P, t1 + 1, hb[1]);    // h_lo(t1+1) -> hb[1]
        __syncthreads();
    }

    // ---- final iter: t=2047 (cur=1, NEW=Q, PREV=P) ----
    Q[0] = (i32x4){}; Q[1] = (i32x4){}; Q[2] = (i32x4){};
    mfma2(Q, hb[1], 0);
    if (!grpA) tail(P, 2046, hb[1]);
    __syncthreads();
    mfma2(Q, hb[1], 2);
    if (grpA) tail(Q, 2047, hb[0]);
    __syncthreads();

    // ---- epilogue: B's deferred tail(2047) (h write unused/harmless) ----
    if (!grpA) tail(Q, 2047, hb[0]);
}

// ---------------- launch ----------------

extern "C" void kernel_launch(void* const* d_in, const int* in_sizes, int n_in,
                              void* d_out, int out_size, void* d_ws, size_t ws_size,
                              hipStream_t stream) {
    const float* x   = (const float*)d_in[0];
    const float* Wz  = (const float*)d_in[1];
    const float* bz  = (const float*)d_in[2];
    const float* Wr  = (const float*)d_in[3];
    const float* br  = (const float*)d_in[4];
    const float* Wh  = (const float*)d_in[5];
    const float* bh  = (const float*)d_in[6];
    const float* Uz  = (const float*)d_in[7];
    const float* buz = (const float*)d_in[8];
    const float* Ur  = (const float*)d_in[9];
    const float* bur = (const float*)d_in[10];
    const float* Uh  = (const float*)d_in[11];
    const float* buh = (const float*)d_in[12];

    char* ws = (char*)d_ws;
    // layout: Xh 64MiB | XG 192MiB | Wt 384KiB | Ufrag 192KiB | biascat 3KiB | invU 3KiB
    unsigned short* Xh = (unsigned short*)(ws);
    unsigned short* XG = (unsigned short*)(ws + 67108864);
    unsigned short* Wt = (unsigned short*)(ws + 268435456);
    signed char*    Ufrag = (signed char*)(ws + 268828672);
    float*          biascat = (float*)(ws + 269221888);
    float*          invU = (float*)(ws + 269225984);

    k_cvt_x<<<32768, 256, 0, stream>>>((const float4*)x, (ushort4*)Xh);
    k_prep_w<<<768, 256, 0, stream>>>(Wz, Wr, Wh, bz, br, bh, buz, bur, Wt, biascat);
    k_prep_uq<<<768, 256, 0, stream>>>(Uz, Ur, Uh, Ufrag, invU);

    dim3 g1(M_TOTAL / 128, NGATE / 128);
    k_gemm_x<<<g1, 256, 0, stream>>>(Xh, Wt, biascat, XG);

    k_gru<<<BATCH, 1024, 0, stream>>>((const i32x4*)Ufrag, invU, XG, buh, (float*)d_out);
}

// Round 11
// 1292.733 us; speedup vs baseline: 1.1912x; 1.1912x over previous
//
#include <hip/hip_runtime.h>
#include <hip/hip_bf16.h>
#include <hip/hip_fp16.h>

// GRU B=64 S=2048 I=256 H=256, fp32 in/out.
// Phase 1: XG[m][768] = x@[Wz|Wr|Wh] + bias  (fp16 MFMA, fp32 accum)
// Phase 2 (R11): i8 K=64 MFMA recurrence, 4 waves (1/SIMD), zero-redundancy
//   tail. R9 decomposition: 1453cy/step = 773 MFMA pipe (floor) + ~680
//   overhead, of which ~808cy is VALU issue = 4-waves/SIMD redundant tail.
//   R10's split-K failed (intra-wave MFMA+tail serial; 2nd barrier).
//   Now: 256 thr, wave owns 4 N-tiles (48 MFMA/wave = per-SIMD pipe work
//   unchanged); tail distributed by lane group (l4 -> tile l4): all 64
//   lanes process UNIQUE cols (acc picked by 3 cndmask/gate); coalesced
//   full-wave out/h writes. waves_per_eu(1,1) -> 512 unified regs; uf
//   (192) -> AGPR, MFMA reads B from AGPR at full rate (R8/R9 evidence).

#define S_LEN 2048
#define BATCH 64
#define HDIM  256
#define NGATE 768
#define M_TOTAL (BATCH * S_LEN)  // 131072

typedef _Float16 h8_t __attribute__((ext_vector_type(8)));
typedef float    f32x4 __attribute__((ext_vector_type(4)));
typedef int      i32x4 __attribute__((ext_vector_type(4)));

static __device__ __forceinline__ float h2f(unsigned short s) {
    _Float16 h; __builtin_memcpy(&h, &s, 2); return (float)h;
}
static __device__ __forceinline__ unsigned short f2h(float f) {
    _Float16 h = (_Float16)f; unsigned short s; __builtin_memcpy(&s, &h, 2); return s;
}

static __device__ __forceinline__ float sigmoid_fast(float x) {
    float e = __builtin_amdgcn_exp2f(-1.44269504088896341f * x);
    return __builtin_amdgcn_rcpf(1.0f + e);
}
static __device__ __forceinline__ float tanh_fast(float x) {
    return 2.0f * sigmoid_fast(2.0f * x) - 1.0f;
}

// ---------------- prep kernels ----------------

__global__ void k_cvt_x(const float4* __restrict__ x4, ushort4* __restrict__ xh4) {
    int i = blockIdx.x * blockDim.x + threadIdx.x;
    float4 v = x4[i];
    ushort4 o;
    o.x = f2h(v.x); o.y = f2h(v.y); o.z = f2h(v.z); o.w = f2h(v.w);
    xh4[i] = o;
}

__global__ void k_prep_w(const float* __restrict__ Wz, const float* __restrict__ Wr,
                         const float* __restrict__ Wh,
                         const float* __restrict__ bz, const float* __restrict__ br,
                         const float* __restrict__ bh,
                         const float* __restrict__ buz, const float* __restrict__ bur,
                         unsigned short* __restrict__ Wt, float* __restrict__ biascat) {
    int n = blockIdx.x;       // 0..767
    int k = threadIdx.x;      // 0..255
    int g = n >> 8, h = n & 255;
    const float* W = (g == 0) ? Wz : (g == 1) ? Wr : Wh;
    Wt[n * 256 + k] = f2h(W[k * 256 + h]);
    if (k == 0) {
        float bias = (g == 0) ? (bz[h] + buz[h]) : (g == 1) ? (br[h] + bur[h]) : bh[h];
        biascat[n] = bias;
    }
}

// int8 B-fragments for mfma_i32_16x16x64_i8 + per-column descale factors.
// Lane l supplies B[k][col]: col = nt*16 + (l&15), k = ks*64 + (l>>4)*16 + e.
// Ufrag[(((g*16+nt)*4+ks)*64 + l)*16 + e] = round(U_g[k][col] * s_col)
// invU[g*256+col] = maxk|U| / (127*127)
__global__ void k_prep_uq(const float* __restrict__ Uz, const float* __restrict__ Ur,
                          const float* __restrict__ Uh,
                          signed char* __restrict__ Ufrag, float* __restrict__ invU) {
    int blk = blockIdx.x;           // g*256 + col
    int g = blk >> 8, col = blk & 255;
    int k = threadIdx.x;            // 0..255
    const float* U = (g == 0) ? Uz : (g == 1) ? Ur : Uh;
    float v = U[k * 256 + col];
    __shared__ float red[256];
    red[k] = fabsf(v);
    __syncthreads();
    for (int off = 128; off > 0; off >>= 1) {
        if (k < off) red[k] = fmaxf(red[k], red[k + off]);
        __syncthreads();
    }
    float m = red[0];
    float s = (m > 0.0f) ? 127.0f / m : 0.0f;
    int q = __float2int_rn(v * s);
    q = max(-127, min(127, q));
    int ks = k >> 6, l4 = (k >> 4) & 3, e = k & 15;
    int l = l4 * 16 + (col & 15), nt = col >> 4;
    Ufrag[((size_t)(((g * 16 + nt) * 4 + ks) * 64 + l)) * 16 + e] = (signed char)q;
    if (k == 0) invU[g * 256 + col] = m * (1.0f / 16129.0f);
}

// ---------------- phase 1: input GEMM ----------------

#define LDT 264  // 256 + 8 halves per LDS row

__global__ __launch_bounds__(256) void k_gemm_x(const unsigned short* __restrict__ Xh,
                                                const unsigned short* __restrict__ Wt,
                                                const float* __restrict__ biascat,
                                                unsigned short* __restrict__ XG) {
    __shared__ unsigned short As[128 * LDT];
    __shared__ unsigned short Bs[128 * LDT];
    int tid = threadIdx.x;
    int m0 = blockIdx.x * 128;
    int n0 = blockIdx.y * 128;

    {
        const unsigned short* ga = Xh + (size_t)m0 * 256;
        const unsigned short* gb = Wt + (size_t)n0 * 256;
#pragma unroll
        for (int i = 0; i < 16; i++) {
            int chunk = tid + i * 256;
            int row = chunk >> 5;
            int c8  = (chunk & 31) * 8;
            uint4 va = *(const uint4*)(ga + row * 256 + c8);
            *(uint4*)(As + row * LDT + c8) = va;
            uint4 vb = *(const uint4*)(gb + row * 256 + c8);
            *(uint4*)(Bs + row * LDT + c8) = vb;
        }
    }
    __syncthreads();

    int lane = tid & 63, wv = tid >> 6;
    int mw = (wv & 1) * 64, nw = (wv >> 1) * 64;
    int lr = lane & 15, lg = lane >> 4;

    f32x4 acc[4][4] = {};
#pragma unroll
    for (int k = 0; k < 8; k++) {
        h8_t a[4], b[4];
#pragma unroll
        for (int i = 0; i < 4; i++)
            a[i] = *(const h8_t*)(As + (mw + i * 16 + lr) * LDT + k * 32 + lg * 8);
#pragma unroll
        for (int jj = 0; jj < 4; jj++)
            b[jj] = *(const h8_t*)(Bs + (nw + jj * 16 + lr) * LDT + k * 32 + lg * 8);
#pragma unroll
        for (int i = 0; i < 4; i++)
#pragma unroll
            for (int jj = 0; jj < 4; jj++)
                acc[i][jj] = __builtin_amdgcn_mfma_f32_16x16x32_f16(a[i], b[jj], acc[i][jj], 0, 0, 0);
    }

#pragma unroll
    for (int jj = 0; jj < 4; jj++) {
        int gcol = n0 + nw + jj * 16 + lr;
        float bias = biascat[gcol];
#pragma unroll
        for (int i = 0; i < 4; i++) {
            int grow = m0 + mw + i * 16 + lg * 4;
#pragma unroll
            for (int r = 0; r < 4; r++) {
                XG[(size_t)(grow + r) * NGATE + gcol] = f2h(acc[i][jj][r] + bias);
            }
        }
    }
}

// ---------------- phase 2: recurrence (i8 MFMA, 4 waves) ----------------
// 64 WGs (one per batch row) x 256 threads (4 waves, 1/SIMD).
// Wave w owns N-tiles 4w..4w+3 (48 MFMA/wave/step = full per-SIMD share).
// Tail: lane group l4 handles tile l4 -> every lane owns ONE unique column.

__global__ __launch_bounds__(256) __attribute__((amdgpu_waves_per_eu(1, 1)))
void k_gru(const i32x4* __restrict__ Ufrag,
           const float* __restrict__ invU,
           const unsigned short* __restrict__ XG,
           const float* __restrict__ buh,
           float* __restrict__ out) {
    __shared__ __align__(16) signed char hb[2][256];
    int tid = threadIdx.x;
    int lane = tid & 63, w = tid >> 6;       // w = wave, owns tiles 4w..4w+3
    int l4 = lane >> 4, lc = lane & 15;
    int b = blockIdx.x;
    int c = (w * 4 + l4) * 16 + lc;           // unique tail column per lane

    // preamble: 48 i8 B-fragments (192 regs -> AGPR) = U[:, wave's 64 cols]
    i32x4 uf[3][4][4];
#pragma unroll
    for (int g = 0; g < 3; g++)
#pragma unroll
        for (int i = 0; i < 4; i++)
#pragma unroll
            for (int ks = 0; ks < 4; ks++)
                uf[g][i][ks] = Ufrag[(size_t)((g * 16 + (w * 4 + i)) * 4 + ks) * 64 + lane];
    // pin: asm-touched values cannot be rematerialized into the loop
#pragma unroll
    for (int g = 0; g < 3; g++)
#pragma unroll
        for (int i = 0; i < 4; i++)
#pragma unroll
            for (int ks = 0; ks < 4; ks++)
                asm volatile("" : "+v"(uf[g][i][ks]));

    float invz = invU[0 * 256 + c], invr = invU[1 * 256 + c], invh = invU[2 * 256 + c];
    float buh_c = buh[c];

    if (tid < 64) ((int*)hb[0])[tid] = 0;    // h(-1) = 0

    const unsigned short* xb = XG + (size_t)b * S_LEN * NGATE;
    float* ob = out + (size_t)b * S_LEN * HDIM;

    const unsigned short* xp = xb + c;        // advancing gate-input pointer
    unsigned short pz = xp[0], pr = xp[256], ph = xp[512];  // x(0)
    xp += NGATE;
    float hm = 0.0f;                          // fp32 master h for col c
    bool s0 = (l4 & 1) != 0, s1 = (l4 & 2) != 0;
    __syncthreads();

    for (int t = 0; t < S_LEN; ++t) {
        const signed char* hrow = hb[t & 1];
        signed char* hdst = hb[(t & 1) ^ 1];

        i32x4 acc[3][4] = {};
#pragma unroll
        for (int ks = 0; ks < 4; ks++) {
            // A-frag: h_q[k], k = ks*64 + l4*16 + e; 16B broadcast per lane
            // group, 4 distinct addrs, conflict-free. All A rows identical
            // -> D rows identical -> acc[g][i][0] valid in every lane.
            i32x4 a = *(const i32x4*)(hrow + ks * 64 + l4 * 16);
#pragma unroll
            for (int g = 0; g < 3; g++)
#pragma unroll
                for (int i = 0; i < 4; i++)
                    acc[g][i] = __builtin_amdgcn_mfma_i32_16x16x64_i8(a, uf[g][i][ks], acc[g][i], 0, 0, 0);
        }

        // select this lane's tile (l4) accumulator: 3 cndmask per gate
        int z01 = s0 ? acc[0][1][0] : acc[0][0][0];
        int z23 = s0 ? acc[0][3][0] : acc[0][2][0];
        float vz = (float)(s1 ? z23 : z01) * invz;
        int r01 = s0 ? acc[1][1][0] : acc[1][0][0];
        int r23 = s0 ? acc[1][3][0] : acc[1][2][0];
        float vr = (float)(s1 ? r23 : r01) * invr;
        int h01 = s0 ? acc[2][1][0] : acc[2][0][0];
        int h23 = s0 ? acc[2][3][0] : acc[2][2][0];
        float vh = (float)(s1 ? h23 : h01) * invh;

        float z = sigmoid_fast(h2f(pz) + vz);
        float r = sigmoid_fast(h2f(pr) + vr);
        float cd = tanh_fast(h2f(ph) + r * (vh + buh_c));
        hm = (1.0f - z) * hm + z * cd;

        ob[(size_t)t * HDIM + c] = hm;                     // coalesced 256B/wave
        hdst[c] = (signed char)__float2int_rn(hm * 127.0f);

        pz = xp[0]; pr = xp[256]; ph = xp[512];            // prefetch x(t+1)
        xp += NGATE;
        __syncthreads();
    }
}

// ---------------- launch ----------------

extern "C" void kernel_launch(void* const* d_in, const int* in_sizes, int n_in,
                              void* d_out, int out_size, void* d_ws, size_t ws_size,
                              hipStream_t stream) {
    const float* x   = (const float*)d_in[0];
    const float* Wz  = (const float*)d_in[1];
    const float* bz  = (const float*)d_in[2];
    const float* Wr  = (const float*)d_in[3];
    const float* br  = (const float*)d_in[4];
    const float* Wh  = (const float*)d_in[5];
    const float* bh  = (const float*)d_in[6];
    const float* Uz  = (const float*)d_in[7];
    const float* buz = (const float*)d_in[8];
    const float* Ur  = (const float*)d_in[9];
    const float* bur = (const float*)d_in[10];
    const float* Uh  = (const float*)d_in[11];
    const float* buh = (const float*)d_in[12];

    char* ws = (char*)d_ws;
    // layout: Xh 64MiB | XG 192MiB | Wt 384KiB | Ufrag 192KiB | biascat 3KiB | invU 3KiB
    unsigned short* Xh = (unsigned short*)(ws);
    unsigned short* XG = (unsigned short*)(ws + 67108864);
    unsigned short* Wt = (unsigned short*)(ws + 268435456);
    signed char*    Ufrag = (signed char*)(ws + 268828672);
    float*          biascat = (float*)(ws + 269221888);
    float*          invU = (float*)(ws + 269225984);

    k_cvt_x<<<32768, 256, 0, stream>>>((const float4*)x, (ushort4*)Xh);
    k_prep_w<<<768, 256, 0, stream>>>(Wz, Wr, Wh, bz, br, bh, buz, bur, Wt, biascat);
    k_prep_uq<<<768, 256, 0, stream>>>(Uz, Ur, Uh, Ufrag, invU);

    dim3 g1(M_TOTAL / 128, NGATE / 128);
    k_gemm_x<<<g1, 256, 0, stream>>>(Xh, Wt, biascat, XG);

    k_gru<<<BATCH, 256, 0, stream>>>((const i32x4*)Ufrag, invU, XG, buh, (float*)d_out);
}

// Round 12
// 1281.727 us; speedup vs baseline: 1.2014x; 1.0086x over previous
//
#include <hip/hip_runtime.h>
#include <hip/hip_bf16.h>
#include <hip/hip_fp16.h>

// GRU B=64 S=2048 I=256 H=256, fp32 in/out.
// Phase 1: XG[m][768] = x@[Wz|Wr|Wh] + bias  (fp16 MFMA, fp32 accum)
// Phase 2 (R12): i8 K=64 MFMA recurrence, 8 waves (2/SIMD), low-redundancy
//   distributed tail. Calibration (R9/R11): MFMA pipe busy is pinned at
//   773cy/step (48 MFMA/SIMD x 16.1cy, i8 at ~5 PF); only overhead moves.
//   R11 (1 wave/SIMD): zero hiding -> 560cy exposed (ds wait 120 + tail
//   150 + 48 accvgpr-zero 96 + stores/barrier). R9 (4 waves): 4x redundant
//   tail -> 680. Optimum: 2 waves/SIMD -- wave w owns tiles 2w,2w+1
//   (24 MFMA/wave, 48/SIMD unchanged); tail 2x-redundant (lane tile =
//   2w+(l4&1), 1 cndmask/gate select, l4<2 lanes write); sibling wave's
//   MFMA issue covers tail+ds latency. Zero-init killed: ks=0 MFMA takes
//   a persistent pinned zero quad as C. setprio around MFMA (T5, waves
//   now phase-diverse).

#define S_LEN 2048
#define BATCH 64
#define HDIM  256
#define NGATE 768
#define M_TOTAL (BATCH * S_LEN)  // 131072

typedef _Float16 h8_t __attribute__((ext_vector_type(8)));
typedef float    f32x4 __attribute__((ext_vector_type(4)));
typedef int      i32x4 __attribute__((ext_vector_type(4)));

static __device__ __forceinline__ float h2f(unsigned short s) {
    _Float16 h; __builtin_memcpy(&h, &s, 2); return (float)h;
}
static __device__ __forceinline__ unsigned short f2h(float f) {
    _Float16 h = (_Float16)f; unsigned short s; __builtin_memcpy(&s, &h, 2); return s;
}

static __device__ __forceinline__ float sigmoid_fast(float x) {
    float e = __builtin_amdgcn_exp2f(-1.44269504088896341f * x);
    return __builtin_amdgcn_rcpf(1.0f + e);
}
static __device__ __forceinline__ float tanh_fast(float x) {
    return 2.0f * sigmoid_fast(2.0f * x) - 1.0f;
}

// ---------------- prep kernels ----------------

__global__ void k_cvt_x(const float4* __restrict__ x4, ushort4* __restrict__ xh4) {
    int i = blockIdx.x * blockDim.x + threadIdx.x;
    float4 v = x4[i];
    ushort4 o;
    o.x = f2h(v.x); o.y = f2h(v.y); o.z = f2h(v.z); o.w = f2h(v.w);
    xh4[i] = o;
}

__global__ void k_prep_w(const float* __restrict__ Wz, const float* __restrict__ Wr,
                         const float* __restrict__ Wh,
                         const float* __restrict__ bz, const float* __restrict__ br,
                         const float* __restrict__ bh,
                         const float* __restrict__ buz, const float* __restrict__ bur,
                         unsigned short* __restrict__ Wt, float* __restrict__ biascat) {
    int n = blockIdx.x;       // 0..767
    int k = threadIdx.x;      // 0..255
    int g = n >> 8, h = n & 255;
    const float* W = (g == 0) ? Wz : (g == 1) ? Wr : Wh;
    Wt[n * 256 + k] = f2h(W[k * 256 + h]);
    if (k == 0) {
        float bias = (g == 0) ? (bz[h] + buz[h]) : (g == 1) ? (br[h] + bur[h]) : bh[h];
        biascat[n] = bias;
    }
}

// int8 B-fragments for mfma_i32_16x16x64_i8 + per-column descale factors.
// Lane l supplies B[k][col]: col = nt*16 + (l&15), k = ks*64 + (l>>4)*16 + e.
// Ufrag[(((g*16+nt)*4+ks)*64 + l)*16 + e] = round(U_g[k][col] * s_col)
// invU[g*256+col] = maxk|U| / (127*127)
__global__ void k_prep_uq(const float* __restrict__ Uz, const float* __restrict__ Ur,
                          const float* __restrict__ Uh,
                          signed char* __restrict__ Ufrag, float* __restrict__ invU) {
    int blk = blockIdx.x;           // g*256 + col
    int g = blk >> 8, col = blk & 255;
    int k = threadIdx.x;            // 0..255
    const float* U = (g == 0) ? Uz : (g == 1) ? Ur : Uh;
    float v = U[k * 256 + col];
    __shared__ float red[256];
    red[k] = fabsf(v);
    __syncthreads();
    for (int off = 128; off > 0; off >>= 1) {
        if (k < off) red[k] = fmaxf(red[k], red[k + off]);
        __syncthreads();
    }
    float m = red[0];
    float s = (m > 0.0f) ? 127.0f / m : 0.0f;
    int q = __float2int_rn(v * s);
    q = max(-127, min(127, q));
    int ks = k >> 6, l4 = (k >> 4) & 3, e = k & 15;
    int l = l4 * 16 + (col & 15), nt = col >> 4;
    Ufrag[((size_t)(((g * 16 + nt) * 4 + ks) * 64 + l)) * 16 + e] = (signed char)q;
    if (k == 0) invU[g * 256 + col] = m * (1.0f / 16129.0f);
}

// ---------------- phase 1: input GEMM ----------------

#define LDT 264  // 256 + 8 halves per LDS row

__global__ __launch_bounds__(256) void k_gemm_x(const unsigned short* __restrict__ Xh,
                                                const unsigned short* __restrict__ Wt,
                                                const float* __restrict__ biascat,
                                                unsigned short* __restrict__ XG) {
    __shared__ unsigned short As[128 * LDT];
    __shared__ unsigned short Bs[128 * LDT];
    int tid = threadIdx.x;
    int m0 = blockIdx.x * 128;
    int n0 = blockIdx.y * 128;

    {
        const unsigned short* ga = Xh + (size_t)m0 * 256;
        const unsigned short* gb = Wt + (size_t)n0 * 256;
#pragma unroll
        for (int i = 0; i < 16; i++) {
            int chunk = tid + i * 256;
            int row = chunk >> 5;
            int c8  = (chunk & 31) * 8;
            uint4 va = *(const uint4*)(ga + row * 256 + c8);
            *(uint4*)(As + row * LDT + c8) = va;
            uint4 vb = *(const uint4*)(gb + row * 256 + c8);
            *(uint4*)(Bs + row * LDT + c8) = vb;
        }
    }
    __syncthreads();

    int lane = tid & 63, wv = tid >> 6;
    int mw = (wv & 1) * 64, nw = (wv >> 1) * 64;
    int lr = lane & 15, lg = lane >> 4;

    f32x4 acc[4][4] = {};
#pragma unroll
    for (int k = 0; k < 8; k++) {
        h8_t a[4], b[4];
#pragma unroll
        for (int i = 0; i < 4; i++)
            a[i] = *(const h8_t*)(As + (mw + i * 16 + lr) * LDT + k * 32 + lg * 8);
#pragma unroll
        for (int jj = 0; jj < 4; jj++)
            b[jj] = *(const h8_t*)(Bs + (nw + jj * 16 + lr) * LDT + k * 32 + lg * 8);
#pragma unroll
        for (int i = 0; i < 4; i++)
#pragma unroll
            for (int jj = 0; jj < 4; jj++)
                acc[i][jj] = __builtin_amdgcn_mfma_f32_16x16x32_f16(a[i], b[jj], acc[i][jj], 0, 0, 0);
    }

#pragma unroll
    for (int jj = 0; jj < 4; jj++) {
        int gcol = n0 + nw + jj * 16 + lr;
        float bias = biascat[gcol];
#pragma unroll
        for (int i = 0; i < 4; i++) {
            int grow = m0 + mw + i * 16 + lg * 4;
#pragma unroll
            for (int r = 0; r < 4; r++) {
                XG[(size_t)(grow + r) * NGATE + gcol] = f2h(acc[i][jj][r] + bias);
            }
        }
    }
}

// ---------------- phase 2: recurrence (i8 MFMA, 8 waves) ----------------
// 64 WGs (one per batch row) x 512 threads (8 waves, 2/SIMD).
// Wave w owns N-tiles 2w, 2w+1 (24 MFMA/wave/step; 48/SIMD = pipe floor).
// Tail: lane's tile = 2w + (l4&1); lanes l4>=2 duplicate; l4<2 write.

__global__ __launch_bounds__(512) __attribute__((amdgpu_waves_per_eu(2, 2)))
void k_gru(const i32x4* __restrict__ Ufrag,
           const float* __restrict__ invU,
           const unsigned short* __restrict__ XG,
           const float* __restrict__ buh,
           float* __restrict__ out) {
    __shared__ __align__(16) signed char hb[2][256];
    int tid = threadIdx.x;
    int lane = tid & 63, w = tid >> 6;       // w = wave 0..7, tiles 2w,2w+1
    int l4 = lane >> 4, lc = lane & 15;
    int b = blockIdx.x;
    int sel = l4 & 1;                         // which owned tile this lane tails
    int c = (2 * w + sel) * 16 + lc;          // tail column (2x redundant)
    bool writer = (l4 < 2);

    // preamble: 24 i8 B-fragments (96 regs) = U[:, wave's 32 cols], 3 gates
    i32x4 uf[3][2][4];
#pragma unroll
    for (int g = 0; g < 3; g++)
#pragma unroll
        for (int i = 0; i < 2; i++)
#pragma unroll
            for (int ks = 0; ks < 4; ks++)
                uf[g][i][ks] = Ufrag[(size_t)((g * 16 + (2 * w + i)) * 4 + ks) * 64 + lane];
    // pin: asm-touched values cannot be rematerialized into the loop
#pragma unroll
    for (int g = 0; g < 3; g++)
#pragma unroll
        for (int i = 0; i < 2; i++)
#pragma unroll
            for (int ks = 0; ks < 4; ks++)
                asm volatile("" : "+v"(uf[g][i][ks]));

    // persistent zero quad for ks=0 C-operand (kills per-step acc zeroing)
    i32x4 zc = {};
    asm volatile("" : "+v"(zc));

    float invz = invU[0 * 256 + c], invr = invU[1 * 256 + c], invh = invU[2 * 256 + c];
    float buh_c = buh[c];

    if (tid < 64) ((int*)hb[0])[tid] = 0;    // h(-1) = 0

    const unsigned short* xb = XG + (size_t)b * S_LEN * NGATE;
    float* ob = out + (size_t)b * S_LEN * HDIM;

    const unsigned short* xp = xb + c;        // advancing gate-input pointer
    unsigned short pz = xp[0], pr = xp[256], ph = xp[512];  // x(0)
    xp += NGATE;
    float hm = 0.0f;                          // fp32 master h for col c
    __syncthreads();

    for (int t = 0; t < S_LEN; ++t) {
        const signed char* hrow = hb[t & 1];
        signed char* hdst = hb[(t & 1) ^ 1];

        i32x4 acc[3][2];
        __builtin_amdgcn_s_setprio(1);
        {   // ks = 0: C = persistent zero quad (no accvgpr zero-init)
            i32x4 a = *(const i32x4*)(hrow + l4 * 16);
#pragma unroll
            for (int g = 0; g < 3; g++)
#pragma unroll
                for (int i = 0; i < 2; i++)
                    acc[g][i] = __builtin_amdgcn_mfma_i32_16x16x64_i8(a, uf[g][i][0], zc, 0, 0, 0);
        }
#pragma unroll
        for (int ks = 1; ks < 4; ks++) {
            // A-frag: h_q[k], k = ks*64 + l4*16 + e; 16B broadcast per lane
            // group, 4 distinct addrs, conflict-free. All A rows identical
            // -> D rows identical -> acc[..][0] valid in every lane.
            i32x4 a = *(const i32x4*)(hrow + ks * 64 + l4 * 16);
#pragma unroll
            for (int g = 0; g < 3; g++)
#pragma unroll
                for (int i = 0; i < 2; i++)
                    acc[g][i] = __builtin_amdgcn_mfma_i32_16x16x64_i8(a, uf[g][i][ks], acc[g][i], 0, 0, 0);
        }
        __builtin_amdgcn_s_setprio(0);

        // select this lane's tile accumulator (1 cndmask per gate)
        float vz = (float)(sel ? acc[0][1][0] : acc[0][0][0]) * invz;
        float vr = (float)(sel ? acc[1][1][0] : acc[1][0][0]) * invr;
        float vh = (float)(sel ? acc[2][1][0] : acc[2][0][0]) * invh;

        float z = sigmoid_fast(h2f(pz) + vz);
        float r = sigmoid_fast(h2f(pr) + vr);
        float cd = tanh_fast(h2f(ph) + r * (vh + buh_c));
        hm = (1.0f - z) * hm + z * cd;

        if (writer) {
            ob[(size_t)t * HDIM + c] = hm;
            hdst[c] = (signed char)__float2int_rn(hm * 127.0f);
        }

        pz = xp[0]; pr = xp[256]; ph = xp[512];            // prefetch x(t+1)
        xp += NGATE;
        __syncthreads();
    }
}

// ---------------- launch ----------------

extern "C" void kernel_launch(void* const* d_in, const int* in_sizes, int n_in,
                              void* d_out, int out_size, void* d_ws, size_t ws_size,
                              hipStream_t stream) {
    const float* x   = (const float*)d_in[0];
    const float* Wz  = (const float*)d_in[1];
    const float* bz  = (const float*)d_in[2];
    const float* Wr  = (const float*)d_in[3];
    const float* br  = (const float*)d_in[4];
    const float* Wh  = (const float*)d_in[5];
    const float* bh  = (const float*)d_in[6];
    const float* Uz  = (const float*)d_in[7];
    const float* buz = (const float*)d_in[8];
    const float* Ur  = (const float*)d_in[9];
    const float* bur = (const float*)d_in[10];
    const float* Uh  = (const float*)d_in[11];
    const float* buh = (const float*)d_in[12];

    char* ws = (char*)d_ws;
    // layout: Xh 64MiB | XG 192MiB | Wt 384KiB | Ufrag 192KiB | biascat 3KiB | invU 3KiB
    unsigned short* Xh = (unsigned short*)(ws);
    unsigned short* XG = (unsigned short*)(ws + 67108864);
    unsigned short* Wt = (unsigned short*)(ws + 268435456);
    signed char*    Ufrag = (signed char*)(ws + 268828672);
    float*          biascat = (float*)(ws + 269221888);
    float*          invU = (float*)(ws + 269225984);

    k_cvt_x<<<32768, 256, 0, stream>>>((const float4*)x, (ushort4*)Xh);
    k_prep_w<<<768, 256, 0, stream>>>(Wz, Wr, Wh, bz, br, bh, buz, bur, Wt, biascat);
    k_prep_uq<<<768, 256, 0, stream>>>(Uz, Ur, Uh, Ufrag, invU);

    dim3 g1(M_TOTAL / 128, NGATE / 128);
    k_gemm_x<<<g1, 256, 0, stream>>>(Xh, Wt, biascat, XG);

    k_gru<<<BATCH, 512, 0, stream>>>((const i32x4*)Ufrag, invU, XG, buh, (float*)d_out);
}